// Round 1
// baseline (1802.193 us; speedup 1.0000x reference)
//
#include <hip/hip_runtime.h>
#include <math.h>

#define SEQ 197
#define EMB 768
#define NH  12
#define HD  64
#define NE  28   // embedding table rows (2*13+1+1)

#define BM 128
#define BN 128
#define BK 16

// ---------------------------------------------------------------------------
// GEMM: C[m][n] = sum_k A[m][k] * W[n][k] + bias[n]
// mode 0: qkv fused (grid.y = 18 -> mat = nt/6 selects Wq/Wk/Wv), output
//         scattered to (b, h, s, d) layout.
// mode 1: output projection (grid.y = 6), output flat row-major (M, 768).
// ---------------------------------------------------------------------------
__global__ __launch_bounds__(256) void gemm_k(
    const float* __restrict__ A,
    const float* __restrict__ W0, const float* __restrict__ W1, const float* __restrict__ W2,
    const float* __restrict__ b0, const float* __restrict__ b1, const float* __restrict__ b2,
    float* __restrict__ O0, float* __restrict__ O1, float* __restrict__ O2,
    int M, int mode)
{
    __shared__ __align__(16) float As[BK][BM + 4];   // [k][m], stride 132 keeps 16B align
    __shared__ __align__(16) float Bs[BK][BN + 4];   // [k][n]

    const int mt  = blockIdx.x;
    const int nt  = blockIdx.y;
    const int mat = nt / 6;
    const int ntl = nt % 6;
    const float* __restrict__ W    = (mat == 0) ? W0 : (mat == 1 ? W1 : W2);
    const float* __restrict__ bias = (mat == 0) ? b0 : (mat == 1 ? b1 : b2);
    float* __restrict__ O          = (mat == 0) ? O0 : (mat == 1 ? O1 : O2);

    const int m0  = mt * BM;
    const int n0  = ntl * BN;
    const int tid = threadIdx.x;
    const int tx  = tid & 15;
    const int ty  = tid >> 4;
    const int lm  = tid >> 2;          // 0..63 (row within tile half)
    const int lk  = (tid & 3) * 4;     // 0,4,8,12 (k offset, float4 granule)

    float acc[8][8];
#pragma unroll
    for (int i = 0; i < 8; i++)
#pragma unroll
        for (int j = 0; j < 8; j++) acc[i][j] = 0.f;

    for (int k0 = 0; k0 < EMB; k0 += BK) {
#pragma unroll
        for (int half = 0; half < 2; half++) {
            const int m  = lm + 64 * half;
            const int gm = m0 + m;
            float4 v = make_float4(0.f, 0.f, 0.f, 0.f);
            if (gm < M) v = *(const float4*)(A + (size_t)gm * EMB + k0 + lk);
            As[lk + 0][m] = v.x; As[lk + 1][m] = v.y;
            As[lk + 2][m] = v.z; As[lk + 3][m] = v.w;
            const int n = lm + 64 * half;   // row of W == output column
            float4 wv = *(const float4*)(W + (size_t)(n0 + n) * EMB + k0 + lk);
            Bs[lk + 0][n] = wv.x; Bs[lk + 1][n] = wv.y;
            Bs[lk + 2][n] = wv.z; Bs[lk + 3][n] = wv.w;
        }
        __syncthreads();
#pragma unroll
        for (int k = 0; k < BK; k++) {
            float a[8], b[8];
            *(float4*)&a[0] = *(const float4*)&As[k][ty * 4];
            *(float4*)&a[4] = *(const float4*)&As[k][64 + ty * 4];
            *(float4*)&b[0] = *(const float4*)&Bs[k][tx * 4];
            *(float4*)&b[4] = *(const float4*)&Bs[k][64 + tx * 4];
#pragma unroll
            for (int i = 0; i < 8; i++)
#pragma unroll
                for (int j = 0; j < 8; j++)
                    acc[i][j] = fmaf(a[i], b[j], acc[i][j]);
        }
        __syncthreads();
    }

#pragma unroll
    for (int i = 0; i < 8; i++) {
        const int ml = (i < 4) ? (ty * 4 + i) : (64 + ty * 4 + (i - 4));
        const int gm = m0 + ml;
        if (gm >= M) continue;
        const int bb = gm / SEQ, ss = gm % SEQ;
#pragma unroll
        for (int j = 0; j < 8; j++) {
            const int nl = (j < 4) ? (tx * 4 + j) : (64 + tx * 4 + (j - 4));
            const int e  = n0 + nl;
            const float v = acc[i][j] + bias[e];
            if (mode == 0) {
                // (b, h, s, d)
                O[(((size_t)bb * NH + (e >> 6)) * SEQ + ss) * HD + (e & 63)] = v;
            } else {
                O[(size_t)gm * EMB + e] = v;
            }
        }
    }
}

// ---------------------------------------------------------------------------
// Fused attention: one block per (b, h). K/V staged in LDS (K XOR-swizzled
// for conflict-free per-row b128 reads). Rel-pos q-logits factorized into
// r_x/r_y (S x 28 each, in LDS); rel-pos v-contribution via probability
// histogram over 28 bins + tiny table matmul. 4-query register blocking.
// ---------------------------------------------------------------------------
__global__ __launch_bounds__(256) void attn_k(
    const float* __restrict__ xq, const float* __restrict__ xk, const float* __restrict__ xv,
    const float* __restrict__ q_tab_x, const float* __restrict__ q_tab_y,
    const float* __restrict__ v_tab_x, const float* __restrict__ v_tab_y,
    const int* __restrict__ x_dist, const int* __restrict__ y_dist,
    float* __restrict__ out)
{
    __shared__ __align__(16) float K_s[SEQ * HD];     // swizzled rows
    __shared__ __align__(16) float V_s[SEQ * HD];     // linear rows
    __shared__ float rx_s[SEQ * NE];
    __shared__ float ry_s[SEQ * NE];
    __shared__ float p_s[4][4][SEQ];                  // [wave][qq][k]
    __shared__ float h_s[4][4][2 * NE];               // [wave][qq][x:0..27 | y:28..55]

    const int bh = blockIdx.x;
    const int b  = bh / NH;
    const int h  = bh % NH;
    const float* __restrict__ xq_r = xq + (size_t)bh * SEQ * HD;
    const float* __restrict__ xk_r = xk + (size_t)bh * SEQ * HD;
    const float* __restrict__ xv_r = xv + (size_t)bh * SEQ * HD;

    const int tid  = threadIdx.x;
    const int w    = tid >> 6;
    const int lane = tid & 63;

    // ---- stage K (xor-swizzled 16B blocks) and V (linear) ----
    for (int idx = tid; idx < SEQ * 16; idx += 256) {
        const int k = idx >> 4, db = idx & 15;
        float4 kv = *(const float4*)(xk_r + k * HD + db * 4);
        const int sdb = db ^ (k & 7);
        *(float4*)&K_s[k * HD + sdb * 4] = kv;
        float4 vv = *(const float4*)(xv_r + k * HD + db * 4);
        *(float4*)&V_s[k * HD + db * 4] = vv;
    }
    // ---- r_x/r_y: (S, 28) per table; r[q][e] = sum_{d<32} xq[q,d]*tab[e,d] ----
    for (int o = tid; o < SEQ * 2 * NE; o += 256) {
        const int q = o / (2 * NE);
        const int j = o % (2 * NE);
        const int isx = (j < NE);
        const int e = isx ? j : (j - NE);
        const float* qrow = xq_r + q * HD + (isx ? 0 : 32);
        const float* tab  = (isx ? q_tab_x : q_tab_y) + e * 32;
        float acc = 0.f;
#pragma unroll
        for (int d = 0; d < 32; d += 4) {
            float4 a = *(const float4*)(qrow + d);
            float4 t = *(const float4*)(tab + d);
            acc += a.x * t.x + a.y * t.y + a.z * t.z + a.w * t.w;
        }
        (isx ? rx_s : ry_s)[q * NE + e] = acc;
    }
    __syncthreads();

    const int k0 = lane, k1 = lane + 64, k2 = lane + 128, k3 = lane + 192;
    const bool v3 = (k3 < SEQ);
    const int k3c = v3 ? k3 : 0;
    const int swz = (lane & 7);   // k0..k3 differ by 64 -> same low-3 bits

    for (int q0 = w * 4; q0 < SEQ; q0 += 16) {
        // ---------------- QK^T for 4 query rows ----------------
        float acc[4][4];
#pragma unroll
        for (int qq = 0; qq < 4; qq++)
#pragma unroll
            for (int s = 0; s < 4; s++) acc[qq][s] = 0.f;

        const float* qps[4];
#pragma unroll
        for (int qq = 0; qq < 4; qq++) {
            int qi = q0 + qq; if (qi > SEQ - 1) qi = SEQ - 1;
            qps[qq] = xq_r + qi * HD;
        }
#pragma unroll
        for (int db = 0; db < 16; db++) {
            const int so = ((db ^ swz) << 2);
            float4 kv[4];
            kv[0] = *(const float4*)&K_s[k0 * HD + so];
            kv[1] = *(const float4*)&K_s[k1 * HD + so];
            kv[2] = *(const float4*)&K_s[k2 * HD + so];
            kv[3] = *(const float4*)&K_s[k3c * HD + so];
#pragma unroll
            for (int qq = 0; qq < 4; qq++) {
                float4 qv = *(const float4*)(qps[qq] + db * 4);
#pragma unroll
                for (int s = 0; s < 4; s++) {
                    acc[qq][s] = fmaf(qv.x, kv[s].x, acc[qq][s]);
                    acc[qq][s] = fmaf(qv.y, kv[s].y, acc[qq][s]);
                    acc[qq][s] = fmaf(qv.z, kv[s].z, acc[qq][s]);
                    acc[qq][s] = fmaf(qv.w, kv[s].w, acc[qq][s]);
                }
            }
        }

        // ---------------- softmax + histogram per query ----------------
#pragma unroll
        for (int qq = 0; qq < 4; qq++) {
            const int q = q0 + qq;
            if (q < SEQ) {
                const int* xd = x_dist + q * SEQ;
                const int* yd = y_dist + q * SEQ;
                const int e0x = xd[k0], e1x = xd[k1], e2x = xd[k2], e3x = xd[k3c];
                const int e0y = yd[k0], e1y = yd[k1], e2y = yd[k2], e3y = yd[k3c];
                const float* rx = rx_s + q * NE;
                const float* ry = ry_s + q * NE;
                const float l0 = (acc[qq][0] + rx[e0x] + ry[e0y]) * 0.125f;
                const float l1 = (acc[qq][1] + rx[e1x] + ry[e1y]) * 0.125f;
                const float l2 = (acc[qq][2] + rx[e2x] + ry[e2y]) * 0.125f;
                const float l3 = v3 ? (acc[qq][3] + rx[e3x] + ry[e3y]) * 0.125f : -1e30f;
                float mx = fmaxf(fmaxf(l0, l1), fmaxf(l2, l3));
#pragma unroll
                for (int off = 32; off >= 1; off >>= 1) mx = fmaxf(mx, __shfl_xor(mx, off));
                float p0 = __expf(l0 - mx), p1 = __expf(l1 - mx), p2 = __expf(l2 - mx);
                float p3 = v3 ? __expf(l3 - mx) : 0.f;
                float sm = p0 + p1 + p2 + p3;
#pragma unroll
                for (int off = 32; off >= 1; off >>= 1) sm += __shfl_xor(sm, off);
                const float inv = 1.f / sm;
                p0 *= inv; p1 *= inv; p2 *= inv; p3 *= inv;

                if (lane < 2 * NE) h_s[w][qq][lane] = 0.f;
                p_s[w][qq][k0] = p0;
                p_s[w][qq][k1] = p1;
                p_s[w][qq][k2] = p2;
                if (v3) p_s[w][qq][k3] = p3;
                atomicAdd(&h_s[w][qq][e0x], p0);
                atomicAdd(&h_s[w][qq][NE + e0y], p0);
                atomicAdd(&h_s[w][qq][e1x], p1);
                atomicAdd(&h_s[w][qq][NE + e1y], p1);
                atomicAdd(&h_s[w][qq][e2x], p2);
                atomicAdd(&h_s[w][qq][NE + e2y], p2);
                if (v3) {
                    atomicAdd(&h_s[w][qq][e3x], p3);
                    atomicAdd(&h_s[w][qq][NE + e3y], p3);
                }
            }
        }

        // ---------------- PV (4 queries, lane = (d4, kk) split) ----------------
        const int d4 = (lane & 15) * 4;
        const int kk = lane >> 4;
        float4 o4[4];
#pragma unroll
        for (int qq = 0; qq < 4; qq++) o4[qq] = make_float4(0.f, 0.f, 0.f, 0.f);

        for (int kb = 0; kb < SEQ; kb += 4) {
            const int k  = kb + kk;
            const bool ok = (k < SEQ);
            const int kc = ok ? k : 0;
            float4 vv = *(const float4*)&V_s[kc * HD + d4];
#pragma unroll
            for (int qq = 0; qq < 4; qq++) {
                const float p = ok ? p_s[w][qq][k] : 0.f;
                o4[qq].x = fmaf(p, vv.x, o4[qq].x);
                o4[qq].y = fmaf(p, vv.y, o4[qq].y);
                o4[qq].z = fmaf(p, vv.z, o4[qq].z);
                o4[qq].w = fmaf(p, vv.w, o4[qq].w);
            }
        }
#pragma unroll
        for (int qq = 0; qq < 4; qq++) {
            o4[qq].x += __shfl_xor(o4[qq].x, 16); o4[qq].x += __shfl_xor(o4[qq].x, 32);
            o4[qq].y += __shfl_xor(o4[qq].y, 16); o4[qq].y += __shfl_xor(o4[qq].y, 32);
            o4[qq].z += __shfl_xor(o4[qq].z, 16); o4[qq].z += __shfl_xor(o4[qq].z, 32);
            o4[qq].w += __shfl_xor(o4[qq].w, 16); o4[qq].w += __shfl_xor(o4[qq].w, 32);
        }

        if (kk == 0) {
            const bool isx = (d4 < 32);
            const int dl = d4 & 31;
            const float* tab = (isx ? v_tab_x : v_tab_y) + dl;
#pragma unroll
            for (int e = 0; e < NE; e++) {
                float4 tv = *(const float4*)(tab + e * 32);
#pragma unroll
                for (int qq = 0; qq < 4; qq++) {
                    const float hh = h_s[w][qq][(isx ? 0 : NE) + e];
                    o4[qq].x = fmaf(hh, tv.x, o4[qq].x);
                    o4[qq].y = fmaf(hh, tv.y, o4[qq].y);
                    o4[qq].z = fmaf(hh, tv.z, o4[qq].z);
                    o4[qq].w = fmaf(hh, tv.w, o4[qq].w);
                }
            }
#pragma unroll
            for (int qq = 0; qq < 4; qq++) {
                const int q = q0 + qq;
                if (q < SEQ) {
                    // (b, s, h, d) so the final projection reads contiguous E
                    *(float4*)(out + (((size_t)b * SEQ + q) * NH + h) * HD + d4) = o4[qq];
                }
            }
        }
    }
}

extern "C" void kernel_launch(void* const* d_in, const int* in_sizes, int n_in,
                              void* d_out, int out_size, void* d_ws, size_t ws_size,
                              hipStream_t stream) {
    const float* x       = (const float*)d_in[0];
    const float* Wq      = (const float*)d_in[1];
    const float* bq      = (const float*)d_in[2];
    const float* Wk      = (const float*)d_in[3];
    const float* bk      = (const float*)d_in[4];
    const float* Wv      = (const float*)d_in[5];
    const float* bv      = (const float*)d_in[6];
    const float* Wo      = (const float*)d_in[7];
    const float* bo      = (const float*)d_in[8];
    const float* q_tab_x = (const float*)d_in[9];
    const float* q_tab_y = (const float*)d_in[10];
    const float* v_tab_x = (const float*)d_in[11];
    const float* v_tab_y = (const float*)d_in[12];
    const int*   x_dist  = (const int*)d_in[13];
    const int*   y_dist  = (const int*)d_in[14];
    float* out = (float*)d_out;

    const int M  = in_sizes[0] / EMB;   // B*S = 12608
    const int Bc = M / SEQ;             // 64

    // workspace: xq | xk | xv | attn_out, each M*EMB floats (~148 MB total)
    float* xq = (float*)d_ws;
    float* xk = xq + (size_t)M * EMB;
    float* xv = xk + (size_t)M * EMB;
    float* ao = xv + (size_t)M * EMB;

    dim3 blk(256);
    dim3 g1((M + BM - 1) / BM, 18);
    gemm_k<<<g1, blk, 0, stream>>>(x, Wq, Wk, Wv, bq, bk, bv, xq, xk, xv, M, 0);

    attn_k<<<dim3(Bc * NH), blk, 0, stream>>>(xq, xk, xv, q_tab_x, q_tab_y,
                                              v_tab_x, v_tab_y, x_dist, y_dist, ao);

    dim3 g3((M + BM - 1) / BM, 6);
    gemm_k<<<g3, blk, 0, stream>>>(ao, Wo, Wo, Wo, bo, bo, bo, out, out, out, M, 1);
}